// Round 7
// baseline (224.173 us; speedup 1.0000x reference)
//
#include <hip/hip_runtime.h>
#include <hip/hip_bf16.h>
#include <cstddef>

#define EPS 1e-5f
#define NSLOPE 0.01f
#define L2E 1.44269504f

typedef __attribute__((ext_vector_type(8))) short s16x8;   // 8 bf16 (4 VGPRs)
typedef __attribute__((ext_vector_type(4))) float f32x4;

union BF8 { unsigned short u[8]; s16x8 v; };

static __device__ inline unsigned short f2bf(float f) {
    unsigned int u = __float_as_uint(f);
    u += 0x7fffu + ((u >> 16) & 1u);   // round-to-nearest-even
    return (unsigned short)(u >> 16);
}

static __device__ inline void nt_store4(float* p, f32x4 v) {
    __builtin_nontemporal_store(v, (f32x4*)p);
}

// ---------------- Kernel W: cast weights to bf16 row-major -----------------
__global__ __launch_bounds__(256) void kW(
    const float* __restrict__ W_enc, const float* __restrict__ W0,
    const float* __restrict__ W1,
    unsigned short* __restrict__ Web, unsigned short* __restrict__ W0b,
    unsigned short* __restrict__ W1b)
{
    int idx = blockIdx.x * 256 + threadIdx.x;
    if (idx < 128 * 64) Web[idx] = f2bf(W_enc[idx]);
    if (idx < 128 * 128) { W0b[idx] = f2bf(W0[idx]); W1b[idx] = f2bf(W1[idx]); }
}

// ---------------- Kernel A -------------------------------------------------
// 32 rows/block. 4 waves: w&1 -> 16-row strip, w>>1 -> 64-col half.
// GEMM1 (enc@WencT,K=64) -> +x+b_enc -> LN1 -> GEMM2 (xn@W0T,K=128)
// -> s1,s2 row-dots; h written transposed into hP[b][jtile][128][32] tiles.
__global__ __launch_bounds__(256, 4) void kA(
    const float* __restrict__ x, const float* __restrict__ enc,
    const unsigned short* __restrict__ Web, const float* __restrict__ b_enc,
    const float* __restrict__ g1, const float* __restrict__ b1,
    const unsigned short* __restrict__ W0b, const float* __restrict__ Wa,
    float* __restrict__ xnew, unsigned short* __restrict__ hP,
    float* __restrict__ s1, float* __restrict__ s2)
{
    __shared__ float ys[32][132];             // y rows (f32) for LN
    __shared__ unsigned short xnb[32][136];   // LN output (bf16) A-frags
    __shared__ unsigned short hts[128][40];   // h transposed (bf16)
    __shared__ float ps1[2][32], ps2[2][32];  // s1/s2 partials per col-half

    int t = threadIdx.x;
    int w = t >> 6, lane = t & 63;
    int ml = lane & 15, quad = lane >> 4;
    int mrow = (w & 1) * 16;
    int chalf = (w >> 1) * 64;
    long long R0 = (long long)blockIdx.x * 32;
    int b = (int)(R0 >> 11);
    int jt = (int)((R0 & 2047) >> 5);        // j-tile index within batch

    // ---- GEMM1: acc1 = enc @ WencT (K=64) ----
    f32x4 acc1[4] = {};
    const float* encrow = enc + (R0 + mrow + ml) * 64 + quad * 8;
#pragma unroll
    for (int kb = 0; kb < 2; ++kb) {
        float4 e0 = *(const float4*)(encrow + kb * 32);
        float4 e1 = *(const float4*)(encrow + kb * 32 + 4);
        BF8 af;
        af.u[0] = f2bf(e0.x); af.u[1] = f2bf(e0.y);
        af.u[2] = f2bf(e0.z); af.u[3] = f2bf(e0.w);
        af.u[4] = f2bf(e1.x); af.u[5] = f2bf(e1.y);
        af.u[6] = f2bf(e1.z); af.u[7] = f2bf(e1.w);
#pragma unroll
        for (int ct = 0; ct < 4; ++ct) {
            int n = chalf + ct * 16 + ml;
            s16x8 bf = *(const s16x8*)(Web + n * 64 + kb * 32 + quad * 8);
            acc1[ct] = __builtin_amdgcn_mfma_f32_16x16x32_bf16(af.v, bf, acc1[ct], 0, 0, 0);
        }
    }
#pragma unroll
    for (int ct = 0; ct < 4; ++ct) {
        int col = chalf + ct * 16 + ml;
        float be = b_enc[col];
#pragma unroll
        for (int rg = 0; rg < 4; ++rg) {
            int rl = mrow + quad * 4 + rg;
            long long row = R0 + rl;
            float y = acc1[ct][rg] + x[row * 128 + col] + be;
            xnew[row * 128 + col] = y;
            ys[rl][col] = y;
        }
    }
    __syncthreads();

    // ---- LN1: 8 threads per row ----
    {
        int rl = t >> 3, sub = t & 7;
        float v[16];
        float s = 0.f, q = 0.f;
#pragma unroll
        for (int i = 0; i < 16; ++i) {
            v[i] = ys[rl][sub * 16 + i];
            s += v[i]; q += v[i] * v[i];
        }
#pragma unroll
        for (int m = 1; m < 8; m <<= 1) { s += __shfl_xor(s, m); q += __shfl_xor(q, m); }
        float mean = s * (1.f / 128.f);
        float var = q * (1.f / 128.f) - mean * mean;
        float rstd = rsqrtf(var + EPS);
#pragma unroll
        for (int i = 0; i < 16; ++i) {
            int col = sub * 16 + i;
            float xn = (v[i] - mean) * rstd * g1[col] + b1[col];
            xnb[rl][col] = f2bf(xn);
        }
    }
    __syncthreads();

    // ---- GEMM2: h = xn @ W0T (K=128) ----
    f32x4 acc2[4] = {};
#pragma unroll
    for (int kb = 0; kb < 4; ++kb) {
        s16x8 af = *(const s16x8*)(&xnb[mrow + ml][kb * 32 + quad * 8]);
#pragma unroll
        for (int ct = 0; ct < 4; ++ct) {
            int n = chalf + ct * 16 + ml;
            s16x8 bf = *(const s16x8*)(W0b + n * 128 + kb * 32 + quad * 8);
            acc2[ct] = __builtin_amdgcn_mfma_f32_16x16x32_bf16(af, bf, acc2[ct], 0, 0, 0);
        }
    }

    // ---- epilogue: hts stash + s1/s2 partial dots ----
#pragma unroll
    for (int ct = 0; ct < 4; ++ct) {
        int col = chalf + ct * 16 + ml;
#pragma unroll
        for (int rg = 0; rg < 4; ++rg)
            hts[col][mrow + quad * 4 + rg] = f2bf(acc2[ct][rg]);
    }
#pragma unroll
    for (int rg = 0; rg < 4; ++rg) {
        float p1 = 0.f, p2 = 0.f;
#pragma unroll
        for (int ct = 0; ct < 4; ++ct) {
            int col = chalf + ct * 16 + ml;
            p1 += acc2[ct][rg] * Wa[col];
            p2 += acc2[ct][rg] * Wa[128 + col];
        }
#pragma unroll
        for (int m = 1; m < 16; m <<= 1) { p1 += __shfl_xor(p1, m); p2 += __shfl_xor(p2, m); }
        if (ml == 0) {
            int rl = mrow + quad * 4 + rg;
            ps1[w >> 1][rl] = p1;
            ps2[w >> 1][rl] = p2;
        }
    }
    __syncthreads();
    if (t < 32) {
        s1[R0 + t] = ps1[0][t] + ps1[1][t];
        s2[R0 + t] = ps2[0][t] + ps2[1][t];
    }
    // hP store: tile [128 cc][32 j], fully coalesced
    {
        int c = t >> 1, half = t & 1;
        unsigned short* dst = hP + (((long long)b * 64 + jt) * 128 + c) * 32 + half * 16;
        const unsigned short* srcp = &hts[c][half * 16];
        *(s16x8*)(dst) = *(const s16x8*)(srcp);
        *(s16x8*)(dst + 8) = *(const s16x8*)(srcp + 8);
    }
}

// ---------------- Kernel D: softmax + atten write + atten@h + LN2 + W1 -----
// 32 rows/block (grid 512). 4 waves: w&1 = j-half (1024 each), w>>1 = rowset
// (16 rows each). Halves hP re-read traffic vs 16-row blocks (each block
// serves 2x rows per hP sweep; same-j-half wave pair shares tiles via L1).
// Softmax constants inline (8 rows/wave). XCD swizzle: batch = bid&7 == XCD
// -> per-XCD hP working set = one batch (512 KB, L2-resident).
// FUSED TAIL: j-half-0 waves (2 of them) do residual+LN2+W1^T+ELU in-place.
__global__ __launch_bounds__(256, 4) void kD(
    const float* __restrict__ s1, const float* __restrict__ s2,
    const unsigned short* __restrict__ hP, const float* __restrict__ xnew,
    const float* __restrict__ g2, const float* __restrict__ b2,
    const unsigned short* __restrict__ W1b,
    float* __restrict__ atten, float* __restrict__ out)
{
    __shared__ float Pt[4][16][36];     // per-wave p-transpose buffer
    __shared__ float Rbuf[2][16][132];  // j-half-1 partials, per rowset
    __shared__ float s1sh[32], Csh[32];

    int t = threadIdx.x;
    int w = t >> 6, lane = t & 63;
    int jh = w & 1, rs = w >> 1;
    // bijective XCD-aware swizzle: grid=512=8*64, batch b == bid&7 == XCD
    int bid = blockIdx.x;
    int swz = (bid & 7) * 64 + (bid >> 3);
    int b = swz >> 6;                   // 64 i-tiles (32 rows) per batch
    int it = swz & 63;
    int i0 = it * 32;
    int ml = lane & 15, quad = lane >> 4;

    const float* s2b = s2 + (long long)b * 2048;

    // ---- softmax constants for rows i0..i0+31 (wave w: rows w*8..w*8+7) ----
    float mxs = -1e30f;
    for (int j = lane * 4; j < 2048; j += 256) {
        float4 v = *(const float4*)(s2b + j);
        mxs = fmaxf(fmaxf(mxs, fmaxf(v.x, v.y)), fmaxf(v.z, v.w));
    }
#pragma unroll
    for (int m = 32; m; m >>= 1) mxs = fmaxf(mxs, __shfl_xor(mxs, m));

    float s1r[8], mi[8], miL2[8], li[8];
#pragma unroll
    for (int r = 0; r < 8; ++r) {
        s1r[r] = s1[(long long)b * 2048 + i0 + w * 8 + r];
        float z0 = s1r[r] + mxs;
        mi[r] = fmaxf(z0, NSLOPE * z0);   // lrelu monotone -> row max
        miL2[r] = mi[r] * L2E;
        li[r] = 0.f;
    }
    for (int j = lane * 4; j < 2048; j += 256) {
        float4 v = *(const float4*)(s2b + j);
        float vv[4] = {v.x, v.y, v.z, v.w};
#pragma unroll
        for (int r = 0; r < 8; ++r) {
#pragma unroll
            for (int k = 0; k < 4; ++k) {
                float z = s1r[r] + vv[k];
                float zl = fmaxf(z, NSLOPE * z);
                li[r] += exp2f(fmaf(zl, L2E, -miL2[r]));
            }
        }
    }
#pragma unroll
    for (int r = 0; r < 8; ++r) {
        float l = li[r];
#pragma unroll
        for (int m = 32; m; m >>= 1) l += __shfl_xor(l, m);
        if (lane == 0) {
            s1sh[w * 8 + r] = s1r[r];
            Csh[w * 8 + r] = mi[r] + __logf(l);
        }
    }
    __syncthreads();

    float s1i  = s1sh[rs * 16 + ml];
    float CiL2 = Csh[rs * 16 + ml] * L2E;  // exp(zl-Ci) = exp2(zl*L2E - CiL2)
    const unsigned short* hPb = hP + (long long)b * 64 * 128 * 32;
    int sr = lane >> 3, sc = lane & 7;
    float* abase = atten + ((long long)b * 2048 + i0 + rs * 16) * 2048;

    f32x4 acc[8] = {};
    for (int jj = 0; jj < 1024; jj += 32) {
        int j0 = jh * 1024 + jj;
        int jb = j0 + quad * 8;
        float4 sa = *(const float4*)(s2b + jb);
        float4 sb = *(const float4*)(s2b + jb + 4);
        float zs[8] = {sa.x, sa.y, sa.z, sa.w, sb.x, sb.y, sb.z, sb.w};
        float p[8];
        BF8 af;
#pragma unroll
        for (int k = 0; k < 8; ++k) {
            float z = s1i + zs[k];
            float zl = fmaxf(z, NSLOPE * z);
            p[k] = exp2f(fmaf(zl, L2E, -CiL2));   // = exp(lrelu-m)/l
            af.u[k] = f2bf(p[k]);
        }
        // wave-local LDS transpose -> coalesced 128B-per-row NT stores
        *(f32x4*)&Pt[w][ml][quad * 8]     = *(const f32x4*)&p[0];
        *(f32x4*)&Pt[w][ml][quad * 8 + 4] = *(const f32x4*)&p[4];
        f32x4 r0 = *(const f32x4*)&Pt[w][sr][sc * 4];
        f32x4 r1 = *(const f32x4*)&Pt[w][8 + sr][sc * 4];
        nt_store4(abase + (long long)sr * 2048 + j0 + sc * 4, r0);
        nt_store4(abase + (long long)(8 + sr) * 2048 + j0 + sc * 4, r1);

        const unsigned short* tb = hPb + (long long)(j0 >> 5) * 128 * 32;
#pragma unroll
        for (int ct = 0; ct < 8; ++ct) {
            s16x8 bfrag = *(const s16x8*)(tb + (ct * 16 + ml) * 32 + quad * 8);
            acc[ct] = __builtin_amdgcn_mfma_f32_16x16x32_bf16(af.v, bfrag, acc[ct], 0, 0, 0);
        }
    }

    // ---- combine j-halves ----
    if (jh) {
#pragma unroll
        for (int ct = 0; ct < 8; ++ct)
#pragma unroll
            for (int rg = 0; rg < 4; ++rg)
                Rbuf[rs][quad * 4 + rg][ct * 16 + ml] = acc[ct][rg];
    }
    __syncthreads();
    if (jh) return;                     // j-half-1 waves done

    // ---- fused tail (2 waves, one per rowset): residual+LN2+W1^T+ELU ----
    // rows ii = quad*4+rg (within rowset), cols cc = ct*16+ml
    const float* xrow = xnew + ((long long)b * 2048 + i0 + rs * 16) * 128;
    float v[8][4];
#pragma unroll
    for (int ct = 0; ct < 8; ++ct) {
#pragma unroll
        for (int rg = 0; rg < 4; ++rg) {
            int ii = quad * 4 + rg;
            int cc = ct * 16 + ml;
            v[ct][rg] = acc[ct][rg] + Rbuf[rs][ii][cc] + xrow[ii * 128 + cc];
        }
    }
    // LN2: per-row (rg) sums over 8 regs/lane, then 16-lane tree over ml
    float sm[4] = {}, qm[4] = {};
#pragma unroll
    for (int ct = 0; ct < 8; ++ct)
#pragma unroll
        for (int rg = 0; rg < 4; ++rg) { sm[rg] += v[ct][rg]; qm[rg] += v[ct][rg] * v[ct][rg]; }
#pragma unroll
    for (int rg = 0; rg < 4; ++rg) {
#pragma unroll
        for (int m = 1; m < 16; m <<= 1) {
            sm[rg] += __shfl_xor(sm[rg], m);
            qm[rg] += __shfl_xor(qm[rg], m);
        }
    }
    // LN output (bf16, A-frag layout) into LDS overlaying dead Pt
    // tail wave rs uses Pt[rs*2..rs*2+1] region (4608 B >= 16*136*2 B)
    unsigned short* xnb2 = (unsigned short*)&Pt[rs * 2][0][0];   // [16][136]
#pragma unroll
    for (int rg = 0; rg < 4; ++rg) {
        float mean = sm[rg] * (1.f / 128.f);
        float var = qm[rg] * (1.f / 128.f) - mean * mean;
        float rstd = rsqrtf(var + EPS);
        int ii = quad * 4 + rg;
#pragma unroll
        for (int ct = 0; ct < 8; ++ct) {
            int cc = ct * 16 + ml;
            float xn = (v[ct][rg] - mean) * rstd * g2[cc] + b2[cc];
            xnb2[ii * 136 + cc] = f2bf(xn);
        }
    }
    // single-wave LDS dep: compiler inserts lgkmcnt wait; no barrier needed
    f32x4 acc2[8] = {};
#pragma unroll
    for (int kb = 0; kb < 4; ++kb) {
        s16x8 af = *(const s16x8*)(xnb2 + ml * 136 + kb * 32 + quad * 8);
#pragma unroll
        for (int ct = 0; ct < 8; ++ct) {
            s16x8 bf = *(const s16x8*)(W1b + (ct * 16 + ml) * 128 + kb * 32 + quad * 8);
            acc2[ct] = __builtin_amdgcn_mfma_f32_16x16x32_bf16(af, bf, acc2[ct], 0, 0, 0);
        }
    }
#pragma unroll
    for (int ct = 0; ct < 8; ++ct) {
#pragma unroll
        for (int rg = 0; rg < 4; ++rg) {
            int ii = quad * 4 + rg;
            int cc = ct * 16 + ml;
            float h = acc2[ct][rg];
            float o = h > 0.f ? h : (__expf(h) - 1.f);
            __builtin_nontemporal_store(o,
                &out[((long long)b * 2048 + i0 + rs * 16 + ii) * 128 + cc]);
        }
    }
}

extern "C" void kernel_launch(void* const* d_in, const int* in_sizes, int n_in,
                              void* d_out, int out_size, void* d_ws, size_t ws_size,
                              hipStream_t stream)
{
    const float* x     = (const float*)d_in[0];
    const float* enc   = (const float*)d_in[1];
    const float* W_enc = (const float*)d_in[2];
    const float* b_enc = (const float*)d_in[3];
    const float* g1    = (const float*)d_in[4];
    const float* b1    = (const float*)d_in[5];
    const float* g2    = (const float*)d_in[6];
    const float* b2    = (const float*)d_in[7];
    const float* W0    = (const float*)d_in[8];
    const float* Wa    = (const float*)d_in[9];
    const float* W1    = (const float*)d_in[10];

    float* out = (float*)d_out;
    const long long ROWS = 8LL * 2048;          // 16384
    const long long HN   = ROWS * 128;          // 2097152

    // workspace layout
    float* xnew = (float*)d_ws;                           // 2097152 f32
    float* s1   = xnew + HN;                              // 16384
    float* s2   = s1 + ROWS;                              // 16384
    unsigned short* hP  = (unsigned short*)(s2 + ROWS);   // 2097152 bf16
    unsigned short* Web = hP + HN;                        // 8192
    unsigned short* W0b = Web + 128 * 64;                 // 16384
    unsigned short* W1b = W0b + 128 * 128;                // 16384

    float* atten = out + HN;        // 8*2048*2048 f32 output region

    kW<<<64, 256, 0, stream>>>(W_enc, W0, W1, Web, W0b, W1b);
    kA<<<512, 256, 0, stream>>>(x, enc, Web, b_enc, g1, b1, W0b, Wa,
                                xnew, hP, s1, s2);
    kD<<<512, 256, 0, stream>>>(s1, s2, hP, xnew, g2, b2, W1b, atten, out);
}

// Round 8
// 219.467 us; speedup vs baseline: 1.0214x; 1.0214x over previous
//
#include <hip/hip_runtime.h>
#include <hip/hip_bf16.h>
#include <cstddef>

#define EPS 1e-5f
#define NSLOPE 0.01f
#define L2E 1.44269504f

typedef __attribute__((ext_vector_type(8))) short s16x8;   // 8 bf16 (4 VGPRs)
typedef __attribute__((ext_vector_type(4))) float f32x4;

union BF8 { unsigned short u[8]; s16x8 v; };

static __device__ inline unsigned short f2bf(float f) {
    unsigned int u = __float_as_uint(f);
    u += 0x7fffu + ((u >> 16) & 1u);   // round-to-nearest-even
    return (unsigned short)(u >> 16);
}

static __device__ inline s16x8 cast8(const float* __restrict__ p) {
    float4 a = *(const float4*)p;
    float4 b = *(const float4*)(p + 4);
    BF8 r;
    r.u[0] = f2bf(a.x); r.u[1] = f2bf(a.y); r.u[2] = f2bf(a.z); r.u[3] = f2bf(a.w);
    r.u[4] = f2bf(b.x); r.u[5] = f2bf(b.y); r.u[6] = f2bf(b.z); r.u[7] = f2bf(b.w);
    return r.v;
}

static __device__ inline void nt_store4(float* p, f32x4 v) {
    __builtin_nontemporal_store(v, (f32x4*)p);
}

// ---------------- Kernel A -------------------------------------------------
// 32 rows/block. 4 waves: w&1 -> 16-row strip, w>>1 -> 64-col half.
// GEMM1 (enc@WencT,K=64) -> +x+b_enc -> LN1 -> GEMM2 (xn@W0T,K=128)
// -> s1,s2 row-dots; h written transposed into hP[b][jtile][128][32] tiles.
// Weight B-frags cast inline from f32 (W_enc/W0 are L2-hot; identical f2bf
// RNE as the old kW) -> kW launch deleted. Blocks 0..63 also cast W1->W1b
// in the epilogue (ready before kD's fused tail consumes it).
__global__ __launch_bounds__(256, 4) void kA(
    const float* __restrict__ x, const float* __restrict__ enc,
    const float* __restrict__ W_enc, const float* __restrict__ b_enc,
    const float* __restrict__ g1, const float* __restrict__ b1,
    const float* __restrict__ W0, const float* __restrict__ Wa,
    const float* __restrict__ W1,
    float* __restrict__ xnew, unsigned short* __restrict__ hP,
    float* __restrict__ s1, float* __restrict__ s2,
    unsigned short* __restrict__ W1b)
{
    __shared__ float ys[32][132];             // y rows (f32) for LN
    __shared__ unsigned short xnb[32][136];   // LN output (bf16) A-frags
    __shared__ unsigned short hts[128][40];   // h transposed (bf16)
    __shared__ float ps1[2][32], ps2[2][32];  // s1/s2 partials per col-half

    int t = threadIdx.x;
    int w = t >> 6, lane = t & 63;
    int ml = lane & 15, quad = lane >> 4;
    int mrow = (w & 1) * 16;
    int chalf = (w >> 1) * 64;
    long long R0 = (long long)blockIdx.x * 32;
    int b = (int)(R0 >> 11);
    int jt = (int)((R0 & 2047) >> 5);        // j-tile index within batch

    // ---- GEMM1: acc1 = enc @ WencT (K=64) ----
    f32x4 acc1[4] = {};
    const float* encrow = enc + (R0 + mrow + ml) * 64 + quad * 8;
#pragma unroll
    for (int kb = 0; kb < 2; ++kb) {
        float4 e0 = *(const float4*)(encrow + kb * 32);
        float4 e1 = *(const float4*)(encrow + kb * 32 + 4);
        BF8 af;
        af.u[0] = f2bf(e0.x); af.u[1] = f2bf(e0.y);
        af.u[2] = f2bf(e0.z); af.u[3] = f2bf(e0.w);
        af.u[4] = f2bf(e1.x); af.u[5] = f2bf(e1.y);
        af.u[6] = f2bf(e1.z); af.u[7] = f2bf(e1.w);
#pragma unroll
        for (int ct = 0; ct < 4; ++ct) {
            int n = chalf + ct * 16 + ml;
            s16x8 bf = cast8(W_enc + n * 64 + kb * 32 + quad * 8);
            acc1[ct] = __builtin_amdgcn_mfma_f32_16x16x32_bf16(af.v, bf, acc1[ct], 0, 0, 0);
        }
    }
#pragma unroll
    for (int ct = 0; ct < 4; ++ct) {
        int col = chalf + ct * 16 + ml;
        float be = b_enc[col];
#pragma unroll
        for (int rg = 0; rg < 4; ++rg) {
            int rl = mrow + quad * 4 + rg;
            long long row = R0 + rl;
            float y = acc1[ct][rg] + x[row * 128 + col] + be;
            xnew[row * 128 + col] = y;
            ys[rl][col] = y;
        }
    }
    __syncthreads();

    // ---- LN1: 8 threads per row ----
    {
        int rl = t >> 3, sub = t & 7;
        float v[16];
        float s = 0.f, q = 0.f;
#pragma unroll
        for (int i = 0; i < 16; ++i) {
            v[i] = ys[rl][sub * 16 + i];
            s += v[i]; q += v[i] * v[i];
        }
#pragma unroll
        for (int m = 1; m < 8; m <<= 1) { s += __shfl_xor(s, m); q += __shfl_xor(q, m); }
        float mean = s * (1.f / 128.f);
        float var = q * (1.f / 128.f) - mean * mean;
        float rstd = rsqrtf(var + EPS);
#pragma unroll
        for (int i = 0; i < 16; ++i) {
            int col = sub * 16 + i;
            float xn = (v[i] - mean) * rstd * g1[col] + b1[col];
            xnb[rl][col] = f2bf(xn);
        }
    }
    __syncthreads();

    // ---- GEMM2: h = xn @ W0T (K=128) ----
    f32x4 acc2[4] = {};
#pragma unroll
    for (int kb = 0; kb < 4; ++kb) {
        s16x8 af = *(const s16x8*)(&xnb[mrow + ml][kb * 32 + quad * 8]);
#pragma unroll
        for (int ct = 0; ct < 4; ++ct) {
            int n = chalf + ct * 16 + ml;
            s16x8 bf = cast8(W0 + n * 128 + kb * 32 + quad * 8);
            acc2[ct] = __builtin_amdgcn_mfma_f32_16x16x32_bf16(af, bf, acc2[ct], 0, 0, 0);
        }
    }

    // ---- epilogue: hts stash + s1/s2 partial dots ----
#pragma unroll
    for (int ct = 0; ct < 4; ++ct) {
        int col = chalf + ct * 16 + ml;
#pragma unroll
        for (int rg = 0; rg < 4; ++rg)
            hts[col][mrow + quad * 4 + rg] = f2bf(acc2[ct][rg]);
    }
#pragma unroll
    for (int rg = 0; rg < 4; ++rg) {
        float p1 = 0.f, p2 = 0.f;
#pragma unroll
        for (int ct = 0; ct < 4; ++ct) {
            int col = chalf + ct * 16 + ml;
            p1 += acc2[ct][rg] * Wa[col];
            p2 += acc2[ct][rg] * Wa[128 + col];
        }
#pragma unroll
        for (int m = 1; m < 16; m <<= 1) { p1 += __shfl_xor(p1, m); p2 += __shfl_xor(p2, m); }
        if (ml == 0) {
            int rl = mrow + quad * 4 + rg;
            ps1[w >> 1][rl] = p1;
            ps2[w >> 1][rl] = p2;
        }
    }
    __syncthreads();
    if (t < 32) {
        s1[R0 + t] = ps1[0][t] + ps1[1][t];
        s2[R0 + t] = ps2[0][t] + ps2[1][t];
    }
    // hP store: tile [128 cc][32 j], fully coalesced
    {
        int c = t >> 1, half = t & 1;
        unsigned short* dst = hP + (((long long)b * 64 + jt) * 128 + c) * 32 + half * 16;
        const unsigned short* srcp = &hts[c][half * 16];
        *(s16x8*)(dst) = *(const s16x8*)(srcp);
        *(s16x8*)(dst + 8) = *(const s16x8*)(srcp + 8);
    }
    // W1 -> W1b cast (64 blocks x 256 thr covers 16384 elems); kD consumes
    if (blockIdx.x < 64) {
        int idx = blockIdx.x * 256 + t;
        W1b[idx] = f2bf(W1[idx]);
    }
}

// ---------------- Kernel D: softmax + atten write + atten@h + LN2 + W1 -----
// R4 form (measured 220.3us): 16 rows/block, grid 1024 (4 blocks/CU), 4
// waves = j-quarters. R7 A/B showed 32-row blocks (grid 512, 2 blocks/CU)
// are +4us: hP re-read traffic is NOT critical (L2-resident); occupancy is.
// Softmax constants inline (float4 scan, exp2-folded). XCD swizzle: batch =
// bid&7 == XCD -> per-XCD hP working set = one batch (512 KB, L2-resident).
// FUSED TAIL (was kE): wave 0 does residual+LN2+W1^T GEMM+ELU in-place.
__global__ __launch_bounds__(256, 4) void kD(
    const float* __restrict__ s1, const float* __restrict__ s2,
    const unsigned short* __restrict__ hP, const float* __restrict__ xnew,
    const float* __restrict__ g2, const float* __restrict__ b2,
    const unsigned short* __restrict__ W1b,
    float* __restrict__ atten, float* __restrict__ out)
{
    __shared__ float Pt[4][16][36];     // per-wave p-transpose buffer
    __shared__ float Rbuf[3][16][132];  // j-partial reduce
    __shared__ float s1sh[16], Csh[16];

    int t = threadIdx.x;
    int w = t >> 6, lane = t & 63;
    // bijective XCD-aware swizzle: grid=1024=8*128, batch b == bid&7 == XCD
    int bid = blockIdx.x;
    int swz = (bid & 7) * 128 + (bid >> 3);
    int b = swz >> 7;                   // 128 i-tiles (16 rows) per batch
    int it = swz & 127;
    int i0 = it * 16;
    int ml = lane & 15, quad = lane >> 4;

    const float* s2b = s2 + (long long)b * 2048;

    // ---- softmax constants for rows i0..i0+15 (wave w: rows w*4..w*4+3) ----
    // float4 scan: 8 iters for max, 8 iters for all 4 rows' denominators
    float mxs = -1e30f;
    for (int j = lane * 4; j < 2048; j += 256) {
        float4 v = *(const float4*)(s2b + j);
        mxs = fmaxf(fmaxf(mxs, fmaxf(v.x, v.y)), fmaxf(v.z, v.w));
    }
#pragma unroll
    for (int m = 32; m; m >>= 1) mxs = fmaxf(mxs, __shfl_xor(mxs, m));

    float s1r[4], mi[4], miL2[4], li[4];
#pragma unroll
    for (int r = 0; r < 4; ++r) {
        s1r[r] = s1[(long long)b * 2048 + i0 + w * 4 + r];
        float z0 = s1r[r] + mxs;
        mi[r] = fmaxf(z0, NSLOPE * z0);   // lrelu monotone -> row max
        miL2[r] = mi[r] * L2E;
        li[r] = 0.f;
    }
    for (int j = lane * 4; j < 2048; j += 256) {
        float4 v = *(const float4*)(s2b + j);
        float vv[4] = {v.x, v.y, v.z, v.w};
#pragma unroll
        for (int r = 0; r < 4; ++r) {
#pragma unroll
            for (int k = 0; k < 4; ++k) {
                float z = s1r[r] + vv[k];
                float zl = fmaxf(z, NSLOPE * z);
                li[r] += exp2f(fmaf(zl, L2E, -miL2[r]));
            }
        }
    }
#pragma unroll
    for (int r = 0; r < 4; ++r) {
        float l = li[r];
#pragma unroll
        for (int m = 32; m; m >>= 1) l += __shfl_xor(l, m);
        if (lane == 0) {
            s1sh[w * 4 + r] = s1r[r];
            Csh[w * 4 + r] = mi[r] + __logf(l);
        }
    }
    __syncthreads();

    float s1i = s1sh[ml];
    float CiL2 = Csh[ml] * L2E;         // exp(zl-Ci) = exp2(zl*L2E - CiL2)
    const unsigned short* hPb = hP + (long long)b * 64 * 128 * 32;
    int sr = lane >> 3, sc = lane & 7;
    float* abase = atten + ((long long)b * 2048 + i0) * 2048;

    f32x4 acc[8] = {};
    for (int jj = 0; jj < 512; jj += 32) {
        int j0 = w * 512 + jj;
        int jb = j0 + quad * 8;
        float4 sa = *(const float4*)(s2b + jb);
        float4 sb = *(const float4*)(s2b + jb + 4);
        float zs[8] = {sa.x, sa.y, sa.z, sa.w, sb.x, sb.y, sb.z, sb.w};
        float p[8];
        BF8 af;
#pragma unroll
        for (int k = 0; k < 8; ++k) {
            float z = s1i + zs[k];
            float zl = fmaxf(z, NSLOPE * z);
            p[k] = exp2f(fmaf(zl, L2E, -CiL2));   // = exp(lrelu-m)/l
            af.u[k] = f2bf(p[k]);
        }
        // wave-local LDS transpose -> coalesced 128B-per-row NT stores
        *(f32x4*)&Pt[w][ml][quad * 8]     = *(const f32x4*)&p[0];
        *(f32x4*)&Pt[w][ml][quad * 8 + 4] = *(const f32x4*)&p[4];
        f32x4 r0 = *(const f32x4*)&Pt[w][sr][sc * 4];
        f32x4 r1 = *(const f32x4*)&Pt[w][8 + sr][sc * 4];
        nt_store4(abase + (long long)sr * 2048 + j0 + sc * 4, r0);
        nt_store4(abase + (long long)(8 + sr) * 2048 + j0 + sc * 4, r1);

        const unsigned short* tb = hPb + (long long)(j0 >> 5) * 128 * 32;
#pragma unroll
        for (int ct = 0; ct < 8; ++ct) {
            s16x8 bfrag = *(const s16x8*)(tb + (ct * 16 + ml) * 32 + quad * 8);
            acc[ct] = __builtin_amdgcn_mfma_f32_16x16x32_bf16(af.v, bfrag, acc[ct], 0, 0, 0);
        }
    }

    // ---- combine j-quarters ----
    if (w > 0) {
#pragma unroll
        for (int ct = 0; ct < 8; ++ct)
#pragma unroll
            for (int rg = 0; rg < 4; ++rg)
                Rbuf[w - 1][quad * 4 + rg][ct * 16 + ml] = acc[ct][rg];
    }
    __syncthreads();
    if (w > 0) return;                  // waves 1-3 done

    // ---- fused tail (wave 0 only): residual + LN2 + W1^T GEMM + ELU ----
    // rows ii = quad*4+rg, cols cc = ct*16+ml
    const float* xrow = xnew + ((long long)b * 2048 + i0) * 128;
    float v[8][4];
#pragma unroll
    for (int ct = 0; ct < 8; ++ct) {
#pragma unroll
        for (int rg = 0; rg < 4; ++rg) {
            int ii = quad * 4 + rg;
            int cc = ct * 16 + ml;
            v[ct][rg] = acc[ct][rg] + Rbuf[0][ii][cc] + Rbuf[1][ii][cc]
                      + Rbuf[2][ii][cc] + xrow[ii * 128 + cc];
        }
    }
    // LN2: per-row (rg) sums over 8 regs/lane, then 16-lane tree over ml
    float sm[4] = {}, qm[4] = {};
#pragma unroll
    for (int ct = 0; ct < 8; ++ct)
#pragma unroll
        for (int rg = 0; rg < 4; ++rg) { sm[rg] += v[ct][rg]; qm[rg] += v[ct][rg] * v[ct][rg]; }
#pragma unroll
    for (int rg = 0; rg < 4; ++rg) {
#pragma unroll
        for (int m = 1; m < 16; m <<= 1) {
            sm[rg] += __shfl_xor(sm[rg], m);
            qm[rg] += __shfl_xor(qm[rg], m);
        }
    }
    // LN output (bf16, A-frag layout) into LDS overlaying dead Pt
    unsigned short* xnb2 = (unsigned short*)&Pt[0][0][0];   // [16][136]
#pragma unroll
    for (int rg = 0; rg < 4; ++rg) {
        float mean = sm[rg] * (1.f / 128.f);
        float var = qm[rg] * (1.f / 128.f) - mean * mean;
        float rstd = rsqrtf(var + EPS);
        int ii = quad * 4 + rg;
#pragma unroll
        for (int ct = 0; ct < 8; ++ct) {
            int cc = ct * 16 + ml;
            float xn = (v[ct][rg] - mean) * rstd * g2[cc] + b2[cc];
            xnb2[ii * 136 + cc] = f2bf(xn);
        }
    }
    // single-wave LDS dep: compiler inserts lgkmcnt wait; no barrier needed
    f32x4 acc2[8] = {};
#pragma unroll
    for (int kb = 0; kb < 4; ++kb) {
        s16x8 af = *(const s16x8*)(xnb2 + ml * 136 + kb * 32 + quad * 8);
#pragma unroll
        for (int ct = 0; ct < 8; ++ct) {
            s16x8 bf = *(const s16x8*)(W1b + (ct * 16 + ml) * 128 + kb * 32 + quad * 8);
            acc2[ct] = __builtin_amdgcn_mfma_f32_16x16x32_bf16(af, bf, acc2[ct], 0, 0, 0);
        }
    }
#pragma unroll
    for (int ct = 0; ct < 8; ++ct) {
#pragma unroll
        for (int rg = 0; rg < 4; ++rg) {
            int ii = quad * 4 + rg;
            int cc = ct * 16 + ml;
            float h = acc2[ct][rg];
            float o = h > 0.f ? h : (__expf(h) - 1.f);
            __builtin_nontemporal_store(o, &out[((long long)b * 2048 + i0 + ii) * 128 + cc]);
        }
    }
}

extern "C" void kernel_launch(void* const* d_in, const int* in_sizes, int n_in,
                              void* d_out, int out_size, void* d_ws, size_t ws_size,
                              hipStream_t stream)
{
    const float* x     = (const float*)d_in[0];
    const float* enc   = (const float*)d_in[1];
    const float* W_enc = (const float*)d_in[2];
    const float* b_enc = (const float*)d_in[3];
    const float* g1    = (const float*)d_in[4];
    const float* b1    = (const float*)d_in[5];
    const float* g2    = (const float*)d_in[6];
    const float* b2    = (const float*)d_in[7];
    const float* W0    = (const float*)d_in[8];
    const float* Wa    = (const float*)d_in[9];
    const float* W1    = (const float*)d_in[10];

    float* out = (float*)d_out;
    const long long ROWS = 8LL * 2048;          // 16384
    const long long HN   = ROWS * 128;          // 2097152

    // workspace layout
    float* xnew = (float*)d_ws;                           // 2097152 f32
    float* s1   = xnew + HN;                              // 16384
    float* s2   = s1 + ROWS;                              // 16384
    unsigned short* hP  = (unsigned short*)(s2 + ROWS);   // 2097152 bf16
    unsigned short* W1b = hP + HN;                        // 16384

    float* atten = out + HN;        // 8*2048*2048 f32 output region

    kA<<<512, 256, 0, stream>>>(x, enc, W_enc, b_enc, g1, b1, W0, Wa, W1,
                                xnew, hP, s1, s2, W1b);
    kD<<<1024, 256, 0, stream>>>(s1, s2, hP, xnew, g2, b2, W1b, atten, out);
}